// Round 6
// baseline (215.627 us; speedup 1.0000x reference)
//
#include <hip/hip_runtime.h>
#include <math.h>

// Problem constants
#define BB   512   // batch
#define TT   256   // timesteps
#define CNNC 512   // channels
#define VV   37    // vocab
#define HH   8     // hidden
#define G4   32    // 4*H
#define CH   32    // scan chunk length (timesteps)
#define CW   (CH * 128)   // chunk words per block: 32 t x 32 g x 4 seq = 4096 (16 KB)

#define L2E 1.4426950408889634f

// native 4-float vector for nontemporal builtins (HIP float4 is a class type)
typedef float f4_t __attribute__((ext_vector_type(4)));

// Async global->LDS copy, 16 B per lane. LDS dest = wave-uniform base + lane*16.
__device__ __forceinline__ void async_copy16(const float* g, float* l) {
    __builtin_amdgcn_global_load_lds(
        (__attribute__((address_space(1))) void*)g,
        (__attribute__((address_space(3))) void*)l, 16, 0, 0);
}

// DPP cross-lane mov: pure VALU latency. quad_perm 0xB1=xor1, 0x4E=xor2,
// 0x1B=xor3; 0x141=row_half_mirror (xor7); 0x140=row_mirror (xor15).
template <int CTRL>
__device__ __forceinline__ float dpp_f(float x) {
    int r = __builtin_amdgcn_update_dpp(0, __float_as_int(x), CTRL, 0xF, 0xF, true);
    return __int_as_float(r);
}

__device__ __forceinline__ float rcp_f(float x) { return __builtin_amdgcn_rcpf(x); }
__device__ __forceinline__ float exp2_f(float x) { return __builtin_amdgcn_exp2f(x); }

// ---------------------------------------------------------------------------
// Kernel 1: avg-pool(features) @ W_in.T partial -> featp[half][B][V]
// 50 KB LDS -> 3 blocks/CU. NT loads: features are read-once (51 MB).
// ---------------------------------------------------------------------------
__global__ __launch_bounds__(256) void k_feat(const float* __restrict__ features,
                                              const float* __restrict__ W_in,
                                              const float* __restrict__ b_in,
                                              float* __restrict__ featp) {
    __shared__ __align__(16) float raw[256 * 49];    // 50176 B
    __shared__ float pooled[256];
    const int b = blockIdx.x, half = blockIdx.y, tid = threadIdx.x;
    const f4_t* src =
        (const f4_t*)(features + (size_t)b * CNNC * 49 + half * (256 * 49));
    f4_t* dst = (f4_t*)raw;
    for (int i = tid; i < 256 * 49 / 4; i += 256)
        dst[i] = __builtin_nontemporal_load(&src[i]);
    __syncthreads();
    {
        const float* p = raw + tid * 49;
        float s = 0.f;
        #pragma unroll
        for (int i = 0; i < 49; ++i) s += p[i];
        pooled[tid] = s;
    }
    __syncthreads();
    const int v = tid >> 2, pp = tid & 3;
    if (v < VV) {
        const float* w = W_in + v * CNNC + half * 256 + pp * 64;
        const float* q = pooled + pp * 64;
        float s = 0.f;
        #pragma unroll 16
        for (int i = 0; i < 64; ++i) s += q[i] * w[i];
        s += __shfl_xor(s, 1);
        s += __shfl_xor(s, 2);
        if (pp == 0)
            featp[(half * BB + b) * VV + v] =
                s * (1.f / 49.f) + (half == 0 ? b_in[v] : 0.f);
    }
}

// ---------------------------------------------------------------------------
// Kernel 2: xproj[bg128][t][g][s4] = -(x_t @ W_ih.T + b_ih + b_hh) * scale_g
//   scale_g = L2E (i,f,o rows) / 2*L2E (g rows 16-23), negated.
//   Layout: block bg (8 seqs) feeds TWO k_lstm blocks (2bg: s 0-3, 2bg+1: 4-7).
// ---------------------------------------------------------------------------
#define CSTR 1185   // caption stage stride (odd -> bank spread)
__global__ __launch_bounds__(256) void k_xproj(const float* __restrict__ captions,
                                               const float* __restrict__ W_ih,
                                               const float* __restrict__ b_ih,
                                               const float* __restrict__ b_hh,
                                               const float* __restrict__ featp,
                                               float* __restrict__ xproj) {
    __shared__ float W[G4 * VV];
    __shared__ float bias[G4];
    __shared__ float cap[8 * CSTR];                  // 8 b x 32 rows x 37
    __shared__ __align__(16) float stage[32 * 260];
    const int bg = blockIdx.x, tile = blockIdx.y;
    const int tid = threadIdx.x;
    const int tl = tid >> 3, s = tid & 7;
    for (int i = tid; i < G4 * VV; i += 256) W[i] = W_ih[i];
    if (tid < G4) bias[tid] = b_ih[tid] + b_hh[tid];

    // stage rows [start, start+32) of captions for the block's 8 sequences
    const int t0 = tile * 32;
    const int start = (tile == 0) ? 0 : t0 - 1;
    for (int i = tid; i < 8 * 1184; i += 256) {
        const int s2 = i / 1184;                      // const-div -> mul/shift
        const int off = i - s2 * 1184;
        cap[s2 * CSTR + off] = __builtin_nontemporal_load(
            &captions[((size_t)(bg * 8 + s2) * TT + start) * VV + off]);
    }
    __syncthreads();

    const int b = bg * 8 + s;
    const int lr = (tile == 0) ? tl - 1 : tl;         // local staged row of x
    float xr[VV];
    if (tile == 0 && tl == 0) {
        #pragma unroll
        for (int v = 0; v < VV; ++v)
            xr[v] = featp[b * VV + v] + featp[(BB + b) * VV + v];
    } else {
        const float* x = &cap[s * CSTR + lr * VV];
        #pragma unroll
        for (int v = 0; v < VV; ++v) xr[v] = x[v];
    }

    float acc[G4];
    #pragma unroll
    for (int g = 0; g < G4; ++g) acc[g] = bias[g];
    #pragma unroll
    for (int v = 0; v < VV; ++v) {
        const float xv = xr[v];
        #pragma unroll
        for (int g = 0; g < G4; ++g) acc[g] += xv * W[g * VV + v];
    }
    #pragma unroll
    for (int g = 0; g < G4; ++g) {
        const float sc = (g >= 16 && g < 24) ? (-2.f * L2E) : (-L2E);
        stage[tl * 260 + g * 8 + s] = acc[g] * sc;
    }
    __syncthreads();

    // scatter to the two 4-seq chunks: [bg128][t][g][s4]
    float* outA = xproj + ((size_t)(2 * bg)     * TT + t0) * 128;
    float* outB = xproj + ((size_t)(2 * bg + 1) * TT + t0) * 128;
    for (int f4 = tid; f4 < 2048; f4 += 256) {
        const int t2   = f4 >> 6;          // 0..31
        const int rest = f4 & 63;
        const int g    = rest >> 1;        // 0..31
        const int hf   = rest & 1;
        f4_t val = *(const f4_t*)&stage[t2 * 260 + g * 8 + hf * 4];
        *(f4_t*)((hf ? outB : outA) + t2 * 128 + g * 4) = val;
    }
}

// ---------------------------------------------------------------------------
// Kernel 3: sequential scan, 16 lanes/sequence. lane = (s4, j, r):
//   r=0 computes gates {i (row j), g (row 16+j)}; r=1 {f (row 8+j), o (24+j)}.
//   h broadcast: DPPs within the 16-lane group (both pair lanes hold h_j).
//   Gate exchange within the r-pair: quad_perm-xor1 DPPs.
//   Triple-buffered chunks, s_waitcnt vmcnt(16/48/32) -- never vmcnt(0);
//   h written per-chunk from registers (off the chain, retires next chunk).
// 128 blocks x 64 threads -> 128 CUs, half the R4 per-wave work.
// ---------------------------------------------------------------------------
__global__ __launch_bounds__(64) void k_lstm(const float* __restrict__ W_hh,
                                             const float* __restrict__ xproj,
                                             float* __restrict__ hbuf) {
    __shared__ __align__(16) float buf[3 * CW + 128];   // 3 x 16 KB + pad
    const int lane = threadIdx.x;
    const int s4 = lane >> 4;            // seq within wave (0..3)
    const int q  = lane & 15;
    const int j  = q >> 1;               // hidden unit
    const int r  = q & 1;                // gate role

    const int rowA = r * 8 + j;          // i or f
    const int rowB = 16 + r * 8 + j;     // g or o
    const float scA = -L2E;
    const float scB = r ? -L2E : (-2.f * L2E);
    float wA[HH], wB[HH];
    #pragma unroll
    for (int m = 0; m < HH; ++m) {
        wA[m] = scA * W_hh[rowA * HH + (j ^ m)];
        wB[m] = scB * W_hh[rowB * HH + (j ^ m)];
    }

    const int bg = blockIdx.x;           // 0..127
    const float* xp = xproj + (size_t)bg * (TT * 128);
    float* hb = hbuf + ((size_t)(bg * 4 + s4) * TT) * HH + j;
    const int roff = rowA * 4 + s4;      // per-lane LDS read offset (2-way free)

    // stage chunks 0 and 1 (16 x 1 KB each)
    #pragma unroll
    for (int it = 0; it < 16; ++it)
        async_copy16(xp + (it * 64 + lane) * 4, &buf[it * 256]);
    #pragma unroll
    for (int it = 0; it < 16; ++it)
        async_copy16(xp + CW + (it * 64 + lane) * 4, &buf[CW + it * 256]);

    float h = 0.f, c = 0.f;
    for (int ck = 0; ck < TT / CH; ++ck) {
        // wait for chunk ck's 16 loads = the oldest outstanding vmem ops
        if (ck == 0)      asm volatile("s_waitcnt vmcnt(16)" ::: "memory");
        else if (ck == 7) asm volatile("s_waitcnt vmcnt(32)" ::: "memory");
        else              asm volatile("s_waitcnt vmcnt(48)" ::: "memory");

        const float* base = &buf[(ck % 3) * CW] + roff;
        float hsv[CH];
        float pA = base[0], pB = base[64];
        #pragma unroll
        for (int tl = 0; tl < CH; ++tl) {
            const float nA = base[(tl + 1) * 128];        // next-step prefetch
            const float nB = base[(tl + 1) * 128 + 64];   // (tl=31 -> harmless)

            // h_{j^m} for m=0..7 (masks stay within the 16-lane row)
            const float ha0 = h;
            const float ha1 = dpp_f<0x4E>(h);             // xor2  -> j^1
            const float ha3 = dpp_f<0x141>(h);            // xor7  -> j^3
            const float ha2 = dpp_f<0x4E>(ha3);           // xor5  -> j^2
            const float ha7 = dpp_f<0x140>(h);            // xor15 -> j^7
            const float ha4 = dpp_f<0x141>(ha7);          // xor8  -> j^4
            const float ha5 = dpp_f<0x4E>(ha4);           // xor10 -> j^5
            const float ha6 = dpp_f<0x1B>(ha7);           // xor12 -> j^6

            // two 4-FMA chains per gate (tree: chain 32 -> ~20 cyc)
            float a0 = fmaf(wA[0], ha0, pA);
            a0 = fmaf(wA[1], ha1, a0);
            a0 = fmaf(wA[2], ha2, a0);
            a0 = fmaf(wA[3], ha3, a0);
            float a1 = wA[4] * ha4;
            a1 = fmaf(wA[5], ha5, a1);
            a1 = fmaf(wA[6], ha6, a1);
            a1 = fmaf(wA[7], ha7, a1);
            const float npA = a0 + a1;
            float b0 = fmaf(wB[0], ha0, pB);
            b0 = fmaf(wB[1], ha1, b0);
            b0 = fmaf(wB[2], ha2, b0);
            b0 = fmaf(wB[3], ha3, b0);
            float b1 = wB[4] * ha4;
            b1 = fmaf(wB[5], ha5, b1);
            b1 = fmaf(wB[6], ha6, b1);
            b1 = fmaf(wB[7], ha7, b1);
            const float npB = b0 + b1;

            const float eA = rcp_f(1.f + exp2_f(npA));    // r=0: i ; r=1: f
            const float uB = rcp_f(1.f + exp2_f(npB));    // r=0: raw g ; r=1: o
            const float gg = fmaf(2.f, uB, -1.f);         // tanh(g) on r=0

            const float myU = r ? eA : eA * gg;           // r=0: i*g ; r=1: f
            const float otU = dpp_f<0xB1>(myU);           // pair swap (xor1)
            const float fg  = r ? myU : otU;
            const float igg = r ? otU : myU;
            const float ogx = dpp_f<0xB1>(uB);
            const float og  = r ? uB : ogx;

            c = fmaf(fg, c, igg);
            const float th =
                fmaf(2.f, rcp_f(1.f + exp2_f(c * (-2.f * L2E))), -1.f);
            h = og * th;
            hsv[tl] = h;
            pA = nA; pB = nB;
        }
        // store this chunk's h (off-chain; retires during next chunk)
        if (r == 0) {
            #pragma unroll
            for (int i = 0; i < CH; ++i) hb[(ck * CH + i) * HH] = hsv[i];
        }
        // stage chunk ck+2 into the buffer freed by chunk ck-1
        if (ck + 2 < TT / CH) {
            const float* src = xp + (size_t)(ck + 2) * CW;
            float* db = &buf[((ck + 2) % 3) * CW];
            #pragma unroll
            for (int it = 0; it < 16; ++it)
                async_copy16(src + (it * 64 + lane) * 4, &db[it * 256]);
        }
    }
}

// ---------------------------------------------------------------------------
// Kernel 4: out[b][t][:] = softmax(h_t @ W_out.T + b_out). One block per b.
// Nontemporal float4 stores for the 194 MB write-once output stream.
// ---------------------------------------------------------------------------
__global__ __launch_bounds__(256) void k_out(const float* __restrict__ hbuf,
                                             const float* __restrict__ W_out,
                                             const float* __restrict__ b_out,
                                             float* __restrict__ out) {
    __shared__ float W[VV * HH];
    __shared__ float bo[VV];
    __shared__ __align__(16) float stage[TT * VV];   // 37 KB
    const int b = blockIdx.x, t = threadIdx.x;
    for (int i = t; i < VV * HH; i += 256) W[i] = W_out[i];
    if (t < VV) bo[t] = b_out[t];
    __syncthreads();

    const f4_t* hp = (const f4_t*)(hbuf + ((size_t)b * TT + t) * HH);
    const f4_t h0 = hp[0], h1 = hp[1];
    const float hr[HH] = {h0.x, h0.y, h0.z, h0.w, h1.x, h1.y, h1.z, h1.w};

    float z[VV];
    float m = -1e30f;
    #pragma unroll
    for (int v = 0; v < VV; ++v) {
        float sv = bo[v];
        #pragma unroll
        for (int k = 0; k < HH; ++k) sv += hr[k] * W[v * HH + k];
        z[v] = sv;
        m = fmaxf(m, sv);
    }
    float sum = 0.f;
    #pragma unroll
    for (int v = 0; v < VV; ++v) {
        z[v] = exp2_f((z[v] - m) * L2E);
        sum += z[v];
    }
    const float rs = rcp_f(sum);
    #pragma unroll
    for (int v = 0; v < VV; ++v) stage[t * VV + v] = z[v] * rs;
    __syncthreads();

    f4_t* ob = (f4_t*)(out + (size_t)b * TT * VV);
    const f4_t* sg = (const f4_t*)stage;
    for (int i = t; i < TT * VV / 4; i += 256)
        __builtin_nontemporal_store(sg[i], &ob[i]);
}

// ---------------------------------------------------------------------------
// Workspace (floats): featp@0 (37,888) | xproj@40960 (4,194,304, [bg128][t][g][s4])
//                     hbuf@4235264 (1,048,576, [b][t][j])
// ---------------------------------------------------------------------------
extern "C" void kernel_launch(void* const* d_in, const int* in_sizes, int n_in,
                              void* d_out, int out_size, void* d_ws, size_t ws_size,
                              hipStream_t stream) {
    const float* features = (const float*)d_in[0];
    const float* captions = (const float*)d_in[1];
    const float* W_in     = (const float*)d_in[2];
    const float* b_in     = (const float*)d_in[3];
    const float* W_ih     = (const float*)d_in[4];
    const float* W_hh     = (const float*)d_in[5];
    const float* b_ih     = (const float*)d_in[6];
    const float* b_hh     = (const float*)d_in[7];
    const float* W_out    = (const float*)d_in[8];
    const float* b_out    = (const float*)d_in[9];
    float* out = (float*)d_out;

    float* ws    = (float*)d_ws;
    float* featp = ws;
    float* xproj = ws + 40960;
    float* hbuf  = ws + 40960 + 4194304;

    k_feat <<<dim3(BB, 2), 256, 0, stream>>>(features, W_in, b_in, featp);
    k_xproj<<<dim3(64, 8), 256, 0, stream>>>(captions, W_ih, b_ih, b_hh, featp, xproj);
    k_lstm <<<128,          64, 0, stream>>>(W_hh, xproj, hbuf);
    k_out  <<<BB,          256, 0, stream>>>(hbuf, W_out, b_out, out);
}

// Round 7
// 196.166 us; speedup vs baseline: 1.0992x; 1.0992x over previous
//
#include <hip/hip_runtime.h>
#include <math.h>

// Problem constants
#define BB   512   // batch
#define TT   256   // timesteps
#define CNNC 512   // channels
#define VV   37    // vocab
#define HH   8     // hidden
#define G4   32    // 4*H
#define CH   32    // scan chunk length (timesteps)
#define CW   (CH * 128)   // chunk words per k_lstm block: 32t x 32g x 4seq (16 KB)

#define L2E 1.4426950408889634f

// native 4-float vector for nontemporal builtins (HIP float4 is a class type)
typedef float f4_t __attribute__((ext_vector_type(4)));

// Async global->LDS copy, 16 B per lane. LDS dest = wave-uniform base + lane*16.
__device__ __forceinline__ void async_copy16(const float* g, float* l) {
    __builtin_amdgcn_global_load_lds(
        (__attribute__((address_space(1))) void*)g,
        (__attribute__((address_space(3))) void*)l, 16, 0, 0);
}

// DPP cross-lane mov: pure VALU latency. quad_perm 0xB1=xor1, 0x4E=xor2,
// 0x1B=xor3; 0x141=row_half_mirror (xor7); 0x140=row_mirror (xor15).
template <int CTRL>
__device__ __forceinline__ float dpp_f(float x) {
    int r = __builtin_amdgcn_update_dpp(0, __float_as_int(x), CTRL, 0xF, 0xF, true);
    return __int_as_float(r);
}

__device__ __forceinline__ float rcp_f(float x) { return __builtin_amdgcn_rcpf(x); }
__device__ __forceinline__ float exp2_f(float x) { return __builtin_amdgcn_exp2f(x); }

// ---------------------------------------------------------------------------
// Kernel 1: avg-pool(features) @ W_in.T partial -> featp[quarter][B][V]
// Quarter-channel blocks: 25 KB LDS -> 6 blocks/CU, grid 2048. NT loads
// (features read-once, 51 MB). Partials summed in k_xproj's t=0 path.
// ---------------------------------------------------------------------------
__global__ __launch_bounds__(256) void k_feat(const float* __restrict__ features,
                                              const float* __restrict__ W_in,
                                              const float* __restrict__ b_in,
                                              float* __restrict__ featp) {
    __shared__ __align__(16) float raw[128 * 49];    // 25088 B
    __shared__ float pooled[128];
    const int b = blockIdx.x, qt = blockIdx.y, tid = threadIdx.x;
    const f4_t* src =
        (const f4_t*)(features + (size_t)b * CNNC * 49 + qt * (128 * 49));
    f4_t* dst = (f4_t*)raw;
    for (int i = tid; i < 128 * 49 / 4; i += 256)
        dst[i] = __builtin_nontemporal_load(&src[i]);
    __syncthreads();
    if (tid < 128) {
        const float* p = raw + tid * 49;
        float s = 0.f;
        #pragma unroll
        for (int i = 0; i < 49; ++i) s += p[i];
        pooled[tid] = s;
    }
    __syncthreads();
    const int v = tid >> 2, pp = tid & 3;
    if (v < VV) {
        const float* w = W_in + v * CNNC + qt * 128 + pp * 32;
        const float* q = pooled + pp * 32;
        float s = 0.f;
        #pragma unroll
        for (int i = 0; i < 32; ++i) s += q[i] * w[i];
        s += __shfl_xor(s, 1);
        s += __shfl_xor(s, 2);
        if (pp == 0)
            featp[(qt * BB + b) * VV + v] =
                s * (1.f / 49.f) + (qt == 0 ? b_in[v] : 0.f);
    }
}

// ---------------------------------------------------------------------------
// Kernel 2: xproj[bg128][t][g][s4] = -(x_t @ W_ih.T + b_ih + b_hh) * scale_g
//   scale_g = L2E (i,f,o rows) / 2*L2E (g rows 16-23), negated.
// Block = (bg 0..127, tile 0..7): 4 seqs x 32 t. Thread = (t, s, gate-half):
// 592 FMAs each. LDS ~40 KB -> 4 blocks/CU (was 74.5 KB -> 2). Out-stage is
// one contiguous 16 KB k_lstm chunk (stride 132 -> conflict-free writes).
// ---------------------------------------------------------------------------
#define CAPS 1188   // per-seq caption stage stride (1184+4)
#define SOS  132    // out-stage stride per t (128+4)
__global__ __launch_bounds__(256) void k_xproj(const float* __restrict__ captions,
                                               const float* __restrict__ W_ih,
                                               const float* __restrict__ b_ih,
                                               const float* __restrict__ b_hh,
                                               const float* __restrict__ featp,
                                               float* __restrict__ xproj) {
    __shared__ float W[G4 * VV];                     // 4736 B
    __shared__ float bias[G4];
    __shared__ float cap[4 * CAPS];                  // 19008 B
    __shared__ __align__(16) float so[32 * SOS];     // 16896 B
    const int bg = blockIdx.x, tile = blockIdx.y;
    const int tid = threadIdx.x;
    for (int i = tid; i < G4 * VV; i += 256) W[i] = W_ih[i];
    if (tid < G4) bias[tid] = b_ih[tid] + b_hh[tid];

    // stage caption rows [start, start+32) for the block's 4 sequences
    const int t0 = tile * 32;
    const int start = (tile == 0) ? 0 : t0 - 1;
    for (int i = tid; i < 4 * 1184; i += 256) {
        const int s2 = i / 1184;                      // const-div -> mul/shift
        const int off = i - s2 * 1184;
        cap[s2 * CAPS + off] = __builtin_nontemporal_load(
            &captions[((size_t)(bg * 4 + s2) * TT + start) * VV + off]);
    }
    __syncthreads();

    const int tl = tid >> 3;             // 0..31 local t
    const int s  = (tid >> 1) & 3;       // seq within block
    const int r  = tid & 1;              // gate half (0: rows 0-15, 1: 16-31)
    const int t  = t0 + tl;
    const int b  = bg * 4 + s;

    float xr[VV];
    if (tile == 0 && tl == 0) {
        #pragma unroll
        for (int v = 0; v < VV; ++v)
            xr[v] = featp[b * VV + v] + featp[(BB + b) * VV + v] +
                    featp[(2 * BB + b) * VV + v] + featp[(3 * BB + b) * VV + v];
    } else {
        const int lr = (tile == 0) ? tl - 1 : tl;
        const float* x = &cap[s * CAPS + lr * VV];
        #pragma unroll
        for (int v = 0; v < VV; ++v) xr[v] = x[v];
    }

    const int g0 = r * 16;
    float acc[16];
    #pragma unroll
    for (int g = 0; g < 16; ++g) acc[g] = bias[g0 + g];
    #pragma unroll
    for (int v = 0; v < VV; ++v) {
        const float xv = xr[v];
        #pragma unroll
        for (int g = 0; g < 16; ++g) acc[g] += xv * W[(g0 + g) * VV + v];
    }
    #pragma unroll
    for (int g = 0; g < 16; ++g) {
        const int gg = g0 + g;
        const float sc = (gg >= 16 && gg < 24) ? (-2.f * L2E) : (-L2E);
        so[tl * SOS + gg * 4 + s] = acc[g] * sc;
    }
    __syncthreads();

    // write the 16 KB chunk [t][g][s4] contiguously
    float* chunk = xproj + ((size_t)bg * TT + t0) * 128;
    for (int i = tid; i < 1024; i += 256) {
        const int t2 = i >> 5, rest = i & 31;
        f4_t val = *(const f4_t*)&so[t2 * SOS + rest * 4];
        *(f4_t*)&chunk[t2 * 128 + rest * 4] = val;
    }
}

// ---------------------------------------------------------------------------
// Kernel 3: sequential scan, 16 lanes/sequence (unchanged from R6).
// lane = (s4, j, r): r=0 gates {i,g}, r=1 {f,o}; h broadcast via DPP;
// triple-buffered chunks, vmcnt(16/48/32) never 0; h stored per-chunk.
// ---------------------------------------------------------------------------
__global__ __launch_bounds__(64) void k_lstm(const float* __restrict__ W_hh,
                                             const float* __restrict__ xproj,
                                             float* __restrict__ hbuf) {
    __shared__ __align__(16) float buf[3 * CW + 128];   // 3 x 16 KB + pad
    const int lane = threadIdx.x;
    const int s4 = lane >> 4;
    const int q  = lane & 15;
    const int j  = q >> 1;
    const int r  = q & 1;

    const int rowA = r * 8 + j;          // i or f
    const int rowB = 16 + r * 8 + j;     // g or o
    const float scA = -L2E;
    const float scB = r ? -L2E : (-2.f * L2E);
    float wA[HH], wB[HH];
    #pragma unroll
    for (int m = 0; m < HH; ++m) {
        wA[m] = scA * W_hh[rowA * HH + (j ^ m)];
        wB[m] = scB * W_hh[rowB * HH + (j ^ m)];
    }

    const int bg = blockIdx.x;           // 0..127
    const float* xp = xproj + (size_t)bg * (TT * 128);
    float* hb = hbuf + ((size_t)(bg * 4 + s4) * TT) * HH + j;
    const int roff = rowA * 4 + s4;

    #pragma unroll
    for (int it = 0; it < 16; ++it)
        async_copy16(xp + (it * 64 + lane) * 4, &buf[it * 256]);
    #pragma unroll
    for (int it = 0; it < 16; ++it)
        async_copy16(xp + CW + (it * 64 + lane) * 4, &buf[CW + it * 256]);

    float h = 0.f, c = 0.f;
    for (int ck = 0; ck < TT / CH; ++ck) {
        if (ck == 0)      asm volatile("s_waitcnt vmcnt(16)" ::: "memory");
        else if (ck == 7) asm volatile("s_waitcnt vmcnt(32)" ::: "memory");
        else              asm volatile("s_waitcnt vmcnt(48)" ::: "memory");

        const float* base = &buf[(ck % 3) * CW] + roff;
        float hsv[CH];
        float pA = base[0], pB = base[64];
        #pragma unroll
        for (int tl = 0; tl < CH; ++tl) {
            const float nA = base[(tl + 1) * 128];
            const float nB = base[(tl + 1) * 128 + 64];

            const float ha0 = h;
            const float ha1 = dpp_f<0x4E>(h);             // xor2  -> j^1
            const float ha3 = dpp_f<0x141>(h);            // xor7  -> j^3
            const float ha2 = dpp_f<0x4E>(ha3);           // xor5  -> j^2
            const float ha7 = dpp_f<0x140>(h);            // xor15 -> j^7
            const float ha4 = dpp_f<0x141>(ha7);          // xor8  -> j^4
            const float ha5 = dpp_f<0x4E>(ha4);           // xor10 -> j^5
            const float ha6 = dpp_f<0x1B>(ha7);           // xor12 -> j^6

            float a0 = fmaf(wA[0], ha0, pA);
            a0 = fmaf(wA[1], ha1, a0);
            a0 = fmaf(wA[2], ha2, a0);
            a0 = fmaf(wA[3], ha3, a0);
            float a1 = wA[4] * ha4;
            a1 = fmaf(wA[5], ha5, a1);
            a1 = fmaf(wA[6], ha6, a1);
            a1 = fmaf(wA[7], ha7, a1);
            const float npA = a0 + a1;
            float b0 = fmaf(wB[0], ha0, pB);
            b0 = fmaf(wB[1], ha1, b0);
            b0 = fmaf(wB[2], ha2, b0);
            b0 = fmaf(wB[3], ha3, b0);
            float b1 = wB[4] * ha4;
            b1 = fmaf(wB[5], ha5, b1);
            b1 = fmaf(wB[6], ha6, b1);
            b1 = fmaf(wB[7], ha7, b1);
            const float npB = b0 + b1;

            const float eA = rcp_f(1.f + exp2_f(npA));    // r=0: i ; r=1: f
            const float uB = rcp_f(1.f + exp2_f(npB));    // r=0: raw g ; r=1: o
            const float gg = fmaf(2.f, uB, -1.f);

            const float myU = r ? eA : eA * gg;           // r=0: i*g ; r=1: f
            const float otU = dpp_f<0xB1>(myU);
            const float fg  = r ? myU : otU;
            const float igg = r ? otU : myU;
            const float ogx = dpp_f<0xB1>(uB);
            const float og  = r ? uB : ogx;

            c = fmaf(fg, c, igg);
            const float th =
                fmaf(2.f, rcp_f(1.f + exp2_f(c * (-2.f * L2E))), -1.f);
            h = og * th;
            hsv[tl] = h;
            pA = nA; pB = nB;
        }
        if (r == 0) {
            #pragma unroll
            for (int i = 0; i < CH; ++i) hb[(ck * CH + i) * HH] = hsv[i];
        }
        if (ck + 2 < TT / CH) {
            const float* src = xp + (size_t)(ck + 2) * CW;
            float* db = &buf[((ck + 2) % 3) * CW];
            #pragma unroll
            for (int it = 0; it < 16; ++it)
                async_copy16(src + (it * 64 + lane) * 4, &db[it * 256]);
        }
    }
}

// ---------------------------------------------------------------------------
// Kernel 4: out[b][t][:] = softmax(h_t @ W_out.T + b_out).
// Grid (512 b, 2 halves) x 128 threads: one row each, 20 KB LDS -> ~7
// blocks/CU (was 512 blocks x 38 KB). NT float4 stores (write-once output).
// ---------------------------------------------------------------------------
__global__ __launch_bounds__(128) void k_out(const float* __restrict__ hbuf,
                                             const float* __restrict__ W_out,
                                             const float* __restrict__ b_out,
                                             float* __restrict__ out) {
    __shared__ float W[VV * HH];
    __shared__ float bo[VV];
    __shared__ __align__(16) float stage[128 * VV];  // 18944 B
    const int b = blockIdx.x, half = blockIdx.y, tid = threadIdx.x;
    for (int i = tid; i < VV * HH; i += 128) W[i] = W_out[i];
    if (tid < VV) bo[tid] = b_out[tid];
    __syncthreads();

    const int t = half * 128 + tid;
    const f4_t* hp = (const f4_t*)(hbuf + ((size_t)b * TT + t) * HH);
    const f4_t h0 = hp[0], h1 = hp[1];
    const float hr[HH] = {h0.x, h0.y, h0.z, h0.w, h1.x, h1.y, h1.z, h1.w};

    float z[VV];
    float m = -1e30f;
    #pragma unroll
    for (int v = 0; v < VV; ++v) {
        float sv = bo[v];
        #pragma unroll
        for (int k = 0; k < HH; ++k) sv += hr[k] * W[v * HH + k];
        z[v] = sv;
        m = fmaxf(m, sv);
    }
    float sum = 0.f;
    #pragma unroll
    for (int v = 0; v < VV; ++v) {
        z[v] = exp2_f((z[v] - m) * L2E);
        sum += z[v];
    }
    const float rs = rcp_f(sum);
    #pragma unroll
    for (int v = 0; v < VV; ++v) stage[tid * VV + v] = z[v] * rs;
    __syncthreads();

    f4_t* ob = (f4_t*)(out + ((size_t)b * TT + half * 128) * VV);
    const f4_t* sg = (const f4_t*)stage;
    for (int i = tid; i < 128 * VV / 4; i += 128)
        __builtin_nontemporal_store(sg[i], &ob[i]);
}

// ---------------------------------------------------------------------------
// Workspace (floats): featp@0 (4*512*37=75,776) | xproj@81920 (4,194,304)
//                     hbuf@4276224 (1,048,576)   -- total ~21.3 MB
// ---------------------------------------------------------------------------
extern "C" void kernel_launch(void* const* d_in, const int* in_sizes, int n_in,
                              void* d_out, int out_size, void* d_ws, size_t ws_size,
                              hipStream_t stream) {
    const float* features = (const float*)d_in[0];
    const float* captions = (const float*)d_in[1];
    const float* W_in     = (const float*)d_in[2];
    const float* b_in     = (const float*)d_in[3];
    const float* W_ih     = (const float*)d_in[4];
    const float* W_hh     = (const float*)d_in[5];
    const float* b_ih     = (const float*)d_in[6];
    const float* b_hh     = (const float*)d_in[7];
    const float* W_out    = (const float*)d_in[8];
    const float* b_out    = (const float*)d_in[9];
    float* out = (float*)d_out;

    float* ws    = (float*)d_ws;
    float* featp = ws;
    float* xproj = ws + 81920;
    float* hbuf  = ws + 81920 + 4194304;

    k_feat <<<dim3(BB, 4),  256, 0, stream>>>(features, W_in, b_in, featp);
    k_xproj<<<dim3(128, 8), 256, 0, stream>>>(captions, W_ih, b_ih, b_hh, featp, xproj);
    k_lstm <<<128,           64, 0, stream>>>(W_hh, xproj, hbuf);
    k_out  <<<dim3(BB, 2),  128, 0, stream>>>(hbuf, W_out, b_out, out);
}